// Round 1
// baseline (164.010 us; speedup 1.0000x reference)
//
#include <hip/hip_runtime.h>

#define B_ 64
#define T_ 2048
#define H_ 512
#define A_ 512

typedef unsigned short u16;
typedef __attribute__((ext_vector_type(8))) short bf16x8;
typedef __attribute__((ext_vector_type(4))) float f32x4;

__device__ __forceinline__ u16 f2bf(float f) {
  unsigned u = __float_as_uint(f);
  unsigned r = (u + 0x7FFFu + ((u >> 16) & 1u)) >> 16;  // RNE
  return (u16)r;
}

__device__ __forceinline__ float fast_tanh(float x) {
  // tanh(x) = 1 - 2/(exp(2x)+1); exact at +-inf, no NaN for finite x
  float e = __expf(2.0f * x);
  return 1.0f - 2.0f * __builtin_amdgcn_rcpf(e + 1.0f);
}

// ---------------- K1a: W_enc fp32 -> bf16, fragment-tiled into ws ----------
// unit (16B = 8 bf16) layout: idx = ks*2048 + (a>>4)*64 + q*16 + (a&15)
// holding W_enc[a][ks*32 + q*8 .. +8]
__global__ void k_conv_wenc(const float* __restrict__ W, u16* __restrict__ wsB) {
  int u = blockIdx.x * 256 + threadIdx.x;  // 32768 units
  int a = u >> 6;
  int hq = u & 63;
  int ks = hq >> 2;
  int q = hq & 3;
  const float4* src = (const float4*)(W + a * H_ + hq * 8);
  float4 x0 = src[0], x1 = src[1];
  uint4 pk;
  pk.x = (unsigned)f2bf(x0.x) | ((unsigned)f2bf(x0.y) << 16);
  pk.y = (unsigned)f2bf(x0.z) | ((unsigned)f2bf(x0.w) << 16);
  pk.z = (unsigned)f2bf(x1.x) | ((unsigned)f2bf(x1.y) << 16);
  pk.w = (unsigned)f2bf(x1.z) | ((unsigned)f2bf(x1.w) << 16);
  int dst = ks * 2048 + (a >> 4) * 64 + q * 16 + (a & 15);
  ((uint4*)wsB)[dst] = pk;
}

// ---------------- K1b: dec_proj[b][a] = dot(dec[b,:], W_dec[a,:]) ----------
__global__ void k_decproj(const float* __restrict__ dec, const float* __restrict__ Wd,
                          float* __restrict__ dp) {
  __shared__ float dl[H_];
  int b = blockIdx.y;
  int a0 = blockIdx.x * 64;
  int tid = threadIdx.x;
  dl[tid] = dec[b * H_ + tid];
  dl[tid + 256] = dec[b * H_ + tid + 256];
  __syncthreads();
  int al = tid >> 2, p = tid & 3;  // 4 threads per output a
  const float4* wr = (const float4*)(Wd + (a0 + al) * H_ + p * 128);
  const float4* dv = (const float4*)(dl + p * 128);
  float s = 0.f;
#pragma unroll 8
  for (int i = 0; i < 32; ++i) {
    float4 w4 = wr[i], d4 = dv[i];
    s += w4.x * d4.x + w4.y * d4.y + w4.z * d4.z + w4.w * d4.w;
  }
  s += __shfl_xor(s, 1);
  s += __shfl_xor(s, 2);
  if (p == 0) dp[b * H_ + a0 + al] = s;
}

// ---------------- K2: fused enc_proj GEMM + tanh + V-dot -> scores ---------
// block: 64 rows (one b) x full A=512. 8 waves, wave w owns cols [w*64, w*64+64).
// per wave: 4 m-frags x 4 n-frags of 16x16x32 bf16 MFMA.
__launch_bounds__(512, 1)
__global__ void k_scores(const float* __restrict__ enc, const u16* __restrict__ wsB,
                         const float* __restrict__ dpj, const float* __restrict__ V,
                         float* __restrict__ scores) {
  __shared__ u16 Ab[64 * 32];    // 4 KB, fragment-tiled
  __shared__ u16 Bb[512 * 32];   // 32 KB, fragment-tiled
  __shared__ float red[8][64];
  int tid = threadIdx.x;
  int w = tid >> 6, l = tid & 63;
  int q = l >> 4, r = l & 15;
  int m0 = blockIdx.x * 64;
  int b = m0 >> 11;  // T=2048 rows per b, 64 | 2048

  f32x4 acc[4][4];
#pragma unroll
  for (int m = 0; m < 4; ++m)
#pragma unroll
    for (int n = 0; n < 4; ++n) acc[m][n] = (f32x4){0.f, 0.f, 0.f, 0.f};

  // A-staging decode: thread t writes 8B = half of unit ut
  int ut = tid >> 1, h = tid & 1;
  int smf = ut >> 6, sq = (ut >> 4) & 3, sr = ut & 15;
  int srow = smf * 16 + sr;
  const float* abase = enc + (size_t)(m0 + srow) * H_ + sq * 8 + h * 4;

  for (int ks = 0; ks < 16; ++ks) {
    __syncthreads();  // previous tile's reads complete
    // B: pre-tiled bf16 ws -> LDS via direct-to-LDS 16B loads (linear both sides)
    const u16* bsrc = wsB + (size_t)ks * (512 * 32);
#pragma unroll
    for (int i = 0; i < 4; ++i) {
      int ubase = w * 256 + i * 64;
      __builtin_amdgcn_global_load_lds(
          (const __attribute__((address_space(1))) unsigned int*)(bsrc + (size_t)(ubase + l) * 8),
          (__attribute__((address_space(3))) unsigned int*)(&Bb[ubase * 8]),
          16, 0, 0);
    }
    // A: fp32 -> bf16 -> LDS (fragment order; writes linear in tid, conflict-free)
    float4 x = *((const float4*)(abase + ks * 32));
    uint2 pk;
    pk.x = (unsigned)f2bf(x.x) | ((unsigned)f2bf(x.y) << 16);
    pk.y = (unsigned)f2bf(x.z) | ((unsigned)f2bf(x.w) << 16);
    *((uint2*)&Ab[ut * 8 + h * 4]) = pk;
    __syncthreads();  // staging visible (compiler drains vmcnt/lgkmcnt)

    bf16x8 af[4], bb[4];
#pragma unroll
    for (int m = 0; m < 4; ++m)
      af[m] = *((const bf16x8*)&Ab[(m * 64 + q * 16 + r) * 8]);
#pragma unroll
    for (int n = 0; n < 4; ++n)
      bb[n] = *((const bf16x8*)&Bb[((w * 4 + n) * 64 + q * 16 + r) * 8]);
#pragma unroll
    for (int m = 0; m < 4; ++m)
#pragma unroll
      for (int n = 0; n < 4; ++n)
        acc[m][n] = __builtin_amdgcn_mfma_f32_16x16x32_bf16(af[m], bb[n], acc[m][n], 0, 0, 0);
  }

  // epilogue: scores partial = sum_col V[col]*tanh(acc + dec_proj[b][col])
  float sp[4][4] = {};
  const float* db = dpj + b * A_;
#pragma unroll
  for (int n = 0; n < 4; ++n) {
    int col = w * 64 + n * 16 + r;
    float vv = V[col];
    float dd = db[col];
#pragma unroll
    for (int m = 0; m < 4; ++m)
#pragma unroll
      for (int j = 0; j < 4; ++j)
        sp[m][j] = fmaf(vv, fast_tanh(acc[m][n][j] + dd), sp[m][j]);
  }
  // reduce over the 16 lanes (cols) of each quarter-wave
#pragma unroll
  for (int m = 0; m < 4; ++m)
#pragma unroll
    for (int j = 0; j < 4; ++j) {
      float v = sp[m][j];
      v += __shfl_xor(v, 1);
      v += __shfl_xor(v, 2);
      v += __shfl_xor(v, 4);
      v += __shfl_xor(v, 8);
      sp[m][j] = v;
    }
  // lane r holds all 16 (m,j) sums; pick its assigned one (static selects, no scratch)
  float outv = 0.f;
#pragma unroll
  for (int mm = 0; mm < 4; ++mm)
#pragma unroll
    for (int jj = 0; jj < 4; ++jj)
      if (r == mm * 4 + jj) outv = sp[mm][jj];
  red[w][(r >> 2) * 16 + q * 4 + (r & 3)] = outv;  // row = m*16 + q*4 + j
  __syncthreads();
  if (tid < 64) {
    float s = 0.f;
#pragma unroll
    for (int ww = 0; ww < 8; ++ww) s += red[ww][tid];
    scores[m0 + tid] = s;
  }
}

// ---------------- K3: softmax over T per b -> weights (output) -------------
__global__ void k_softmax(const float* __restrict__ scores, float* __restrict__ wts) {
  __shared__ float rm[4], rs[4];
  int b = blockIdx.x, tid = threadIdx.x;
  float s[8];
#pragma unroll
  for (int i = 0; i < 8; ++i) s[i] = scores[b * T_ + i * 256 + tid];
  float mx = s[0];
#pragma unroll
  for (int i = 1; i < 8; ++i) mx = fmaxf(mx, s[i]);
#pragma unroll
  for (int off = 1; off <= 32; off <<= 1) mx = fmaxf(mx, __shfl_xor(mx, off));
  if ((tid & 63) == 0) rm[tid >> 6] = mx;
  __syncthreads();
  mx = fmaxf(fmaxf(rm[0], rm[1]), fmaxf(rm[2], rm[3]));
  float ex[8], se = 0.f;
#pragma unroll
  for (int i = 0; i < 8; ++i) { ex[i] = __expf(s[i] - mx); se += ex[i]; }
#pragma unroll
  for (int off = 1; off <= 32; off <<= 1) se += __shfl_xor(se, off);
  if ((tid & 63) == 0) rs[tid >> 6] = se;
  __syncthreads();
  se = rs[0] + rs[1] + rs[2] + rs[3];
  float inv = 1.0f / se;
#pragma unroll
  for (int i = 0; i < 8; ++i) wts[b * T_ + i * 256 + tid] = ex[i] * inv;
}

// ---------------- K4: context partials over 256-t chunks -------------------
__global__ void k_ctx_part(const float* __restrict__ enc, const float* __restrict__ wts,
                           float* __restrict__ part) {
  __shared__ float wl[256];
  __shared__ float4 comb[128];
  int tc = blockIdx.x, b = blockIdx.y;
  int tid = threadIdx.x;
  int t0 = tc * 256;
  wl[tid] = wts[b * T_ + t0 + tid];
  __syncthreads();
  int p = tid >> 7, hq = tid & 127;
  const float* ebase = enc + (size_t)(b * T_ + t0 + p * 128) * H_;
  float ax = 0.f, ay = 0.f, az = 0.f, aw = 0.f;
#pragma unroll 4
  for (int i = 0; i < 128; ++i) {
    float wgt = wl[p * 128 + i];
    float4 x = *((const float4*)(ebase + (size_t)i * H_) + hq);
    ax = fmaf(wgt, x.x, ax);
    ay = fmaf(wgt, x.y, ay);
    az = fmaf(wgt, x.z, az);
    aw = fmaf(wgt, x.w, aw);
  }
  if (p == 1) comb[hq] = make_float4(ax, ay, az, aw);
  __syncthreads();
  if (p == 0) {
    float4 o = comb[hq];
    float4 res = make_float4(ax + o.x, ay + o.y, az + o.z, aw + o.w);
    ((float4*)(part + ((size_t)tc * 64 + b) * H_))[hq] = res;
  }
}

// ---------------- K5: reduce 8 partials -> context (output) ----------------
__global__ void k_ctx_red(const float* __restrict__ part, float* __restrict__ ctx) {
  int idx = blockIdx.x * 256 + threadIdx.x;  // 32768 = B*H
  float s = 0.f;
#pragma unroll
  for (int tc = 0; tc < 8; ++tc) s += part[tc * (B_ * H_) + idx];
  ctx[idx] = s;
}

extern "C" void kernel_launch(void* const* d_in, const int* in_sizes, int n_in,
                              void* d_out, int out_size, void* d_ws, size_t ws_size,
                              hipStream_t stream) {
  const float* enc  = (const float*)d_in[0];
  const float* dec  = (const float*)d_in[1];
  const float* Wenc = (const float*)d_in[2];
  const float* Wdec = (const float*)d_in[3];
  const float* V    = (const float*)d_in[4];
  float* out = (float*)d_out;
  char* ws = (char*)d_ws;

  u16* wsB      = (u16*)ws;                       // 512 KB bf16 tiled W_enc
  float* dpj    = (float*)(ws + 512 * 1024);      // 128 KB dec_proj
  float* scores = (float*)(ws + 640 * 1024);      // 512 KB scores
  float* part   = (float*)(ws + 1152 * 1024);     // 1 MB context partials

  float* ctx = out;            // [B,H] = 32768 floats
  float* wts = out + B_ * H_;  // [B,T] = 131072 floats

  hipLaunchKernelGGL(k_conv_wenc, dim3(128), dim3(256), 0, stream, Wenc, wsB);
  hipLaunchKernelGGL(k_decproj, dim3(8, 64), dim3(256), 0, stream, dec, Wdec, dpj);
  hipLaunchKernelGGL(k_scores, dim3(2048), dim3(512), 0, stream, enc, wsB, dpj, V, scores);
  hipLaunchKernelGGL(k_softmax, dim3(64), dim3(256), 0, stream, scores, wts);
  hipLaunchKernelGGL(k_ctx_part, dim3(8, 64), dim3(256), 0, stream, enc, wts, part);
  hipLaunchKernelGGL(k_ctx_red, dim3(128), dim3(256), 0, stream, part, ctx);
}